// Round 11
// baseline (27.075 us; speedup 1.0000x reference)
//
#include <hip/hip_runtime.h>
#include <math.h>

#define NH    16384   // Hadamard size (2^14)
#define NRES  8192
#define NINP  64
#define BATCH 512

typedef float v2f __attribute__((ext_vector_type(2)));

// ---------------- LDS swizzle ------------------------------------------------
// phys = idx ^ (g<<2), g = idx[5:7]^idx[8:10]^idx[11:13]. Bijective, float4-
// aligned. All 6 exchange patterns below have rank-3 lane->quadbank maps
// (verified by hand): conflict-free b128.
__device__ __forceinline__ constexpr int gfold(int v) {
    return ((v >> 5) & 7) ^ ((v >> 8) & 7) ^ ((v >> 11) & 7);
}
__device__ __forceinline__ constexpr int physf(int v) {
    return v ^ (gfold(v) << 2);
}

// ---------------- packed butterfly primitives -------------------------------
__device__ __forceinline__ v2f pk_add(v2f a, v2f b) {
    v2f d;
    asm("v_pk_add_f32 %0, %1, %2" : "=v"(d) : "v"(a), "v"(b));
    return d;
}
__device__ __forceinline__ v2f pk_sub(v2f a, v2f b, v2f negone) {
    v2f d;
    asm("v_pk_fma_f32 %0, %1, %2, %3" : "=v"(d) : "v"(b), "v"(negone), "v"(a));
    return d;
}

// X[16] packs; element f (0..31) = X[f>>1][f&1]. f0 = idx bit0 (in-pack),
// pack bit0 = idx bit1, pack bits 1-3 = j0,j1,j2 (the register bits).
template <int T>
__device__ __forceinline__ void pstage(v2f X[16], v2f negone) {
#pragma unroll
    for (int p = 0; p < 16; ++p) {
        if (!(p & T)) {
            v2f A = X[p], B = X[p | T];
            X[p]     = pk_add(A, B);
            X[p | T] = pk_sub(A, B, negone);
        }
    }
}
__device__ __forceinline__ void vstage0(v2f X[16]) {
#pragma unroll
    for (int p = 0; p < 16; ++p) {
        float a = X[p].x, b = X[p].y;
        X[p].x = a + b;
        X[p].y = a - b;
    }
}
// 3 j-stages (whatever idx bits j currently holds)
__device__ __forceinline__ void jpass(v2f X[16], v2f negone) {
    pstage<2>(X, negone); pstage<4>(X, negone); pstage<8>(X, negone);
}

// ---------------- cross-lane primitives -------------------------------------
template <int CTRL>
__device__ __forceinline__ float dppf(float v) {
    return __builtin_bit_cast(float,
        __builtin_amdgcn_update_dpp(0, __builtin_bit_cast(int, v), CTRL, 0xF, 0xF, true));
}
template <int CTRL>
__device__ __forceinline__ void dpp_swap(float A, float B, bool odd, float& oA, float& oB) {
    float dA = dppf<CTRL>(A), dB = dppf<CTRL>(B);
    oA = odd ? dB : A;
    oB = odd ? B  : dA;
}
__device__ __forceinline__ void pl16_swap(float& a, float& b) {
    asm("v_permlane16_swap_b32 %0, %1" : "+v"(a), "+v"(b));
}
__device__ __forceinline__ void pl32_swap(float& a, float& b) {
    asm("v_permlane32_swap_b32 %0, %1" : "+v"(a), "+v"(b));
}

// Shuffle-exchange: swap all 3 j-bits with the 3 swappable lane bits.
//   j0 (pack stride 2) <-> l0 : DPP quad_perm xor1 (0xB1)
//   j1 (pack stride 4) <-> l4 : v_permlane16_swap_b32
//   j2 (pack stride 8) <-> l5 : v_permlane32_swap_b32
__device__ __forceinline__ void shuffle_exchange(v2f X[16], bool odd0) {
#pragma unroll
    for (int p = 0; p < 16; ++p) if (!(p & 2)) {
        float a0, a1, b0, b1;
        dpp_swap<0xB1>(X[p].x, X[p | 2].x, odd0, a0, b0);
        dpp_swap<0xB1>(X[p].y, X[p | 2].y, odd0, a1, b1);
        X[p] = (v2f){a0, a1}; X[p | 2] = (v2f){b0, b1};
    }
#pragma unroll
    for (int p = 0; p < 16; ++p) if (!(p & 4)) {
        float a = X[p].x, b = X[p | 4].x; pl16_swap(a, b); X[p].x = a; X[p | 4].x = b;
        float c = X[p].y, d = X[p | 4].y; pl16_swap(c, d); X[p].y = c; X[p | 4].y = d;
    }
#pragma unroll
    for (int p = 0; p < 16; ++p) if (!(p & 8)) {
        float a = X[p].x, b = X[p | 8].x; pl32_swap(a, b); X[p].x = a; X[p | 8].x = b;
        float c = X[p].y, d = X[p | 8].y; pl32_swap(c, d); X[p].y = c; X[p | 8].y = d;
    }
}

// g-offset for float4 g (g0,g1,g2 = j0,j1,j2), disjoint bit-fields
#define GOFF(g, G0, G1, G2) \
    (((g) & 1 ? (G0) : 0) | ((g) & 2 ? (G1) : 0) | ((g) & 4 ? (G2) : 0))

#define WRX(Q, G0, G1, G2) do { _Pragma("unroll") \
    for (int g = 0; g < 8; ++g) \
        lds4[(unsigned)((Q) ^ physf(GOFF(g, G0, G1, G2))) >> 2] = \
            make_float4(X[2*g].x, X[2*g].y, X[2*g+1].x, X[2*g+1].y); } while (0)

#define RDX(Q, G0, G1, G2) do { _Pragma("unroll") \
    for (int g = 0; g < 8; ++g) { \
        float4 v = lds4[(unsigned)((Q) ^ physf(GOFF(g, G0, G1, G2))) >> 2]; \
        X[2*g]   = (v2f){v.x, v.y}; \
        X[2*g+1] = (v2f){v.z, v.w}; } } while (0)

// diag multiply: 2 chunks of 4 float4 (bounded liveness)
#define DIAG_MUL(BASE, G0, G1, G2) do { _Pragma("unroll") \
    for (int h = 0; h < 2; ++h) { \
        float4 dv[4]; \
        _Pragma("unroll") for (int k = 0; k < 4; ++k) \
            dv[k] = *(const float4*)((BASE) + GOFF(h * 4 + k, G0, G1, G2)); \
        _Pragma("unroll") for (int k = 0; k < 4; ++k) { \
            const int g = h * 4 + k; \
            X[2*g]   *= (v2f){dv[k].x, dv[k].y}; \
            X[2*g+1] *= (v2f){dv[k].z, dv[k].w}; \
        } \
    } } while (0)

// LDS-only barrier (no vmcnt drain needed: prefetches go to private VGPRs)
#define BAR() asm volatile("s_waitcnt lgkmcnt(0)\n\ts_barrier" ::: "memory")

// Fast erf: erf(z) ~ tanh(z*(1.1283793 + 0.10090*z^2)), max err ~1e-3.
__device__ __forceinline__ float erf_fast(float z) {
    float p = z * z;
    float u = z * fmaf(p, 0.10090f, 1.1283793f);
    float e = __builtin_amdgcn_exp2f(u * 2.8853902f);
    float r = __builtin_amdgcn_rcpf(e + 1.0f);
    return fmaf(-2.0f, r, 1.0f);
}

// ---------------------------------------------------------------------------
// 512 threads: t = w<<6 | l. Custody slots: j0,j1,j2 (reg); swappable lanes
// s0=l0(dpp), s1=l4(pl16), s2=l5(pl32); fixed lanes f0=l1,f1=l2,f2=l3; w0..w2.
// Schedule (idx bits held by j at each pass):
//  p1{2,3,4}+v  S1  p2{5,9,10}  L1  p3{11,12,13}  S2  p4{6,7,8}          layer0
//  diag1  p5{6,7,8}+v  S3  p6{11,12,13}  L2  p7{2,3,4}  S4  p8{5,9,10}   layer1
//  diag2  p9{5,9,10}+v  S5  p10{2,3,4}  L3  p11{6,7,8}  S6  p12{11,12,13} layer2
//  L1 sets: j=(11,12,13) s=(6,7,8) f=(5,9,10) w=(2,3,4)
//  L2 sets: j=(2,3,4)    s=(5,9,10) f=(11,12,13) w=(6,7,8)
//  L3 sets: j=(6,7,8)    s=(11,12,13) f=(2,3,4) w=(5,9,10)
// ---------------------------------------------------------------------------
__global__ __launch_bounds__(512, 2) void st_kernel(
    const float* __restrict__ state, const float* __restrict__ inputs,
    const float* __restrict__ bias,  const float* __restrict__ diag,
    float* __restrict__ out)
{
    __shared__ float4 lds4[NH / 4];
    const int t = threadIdx.x;   // 0..511
    const int r = blockIdx.x;    // 0..511
    const int l = t & 63, w = t >> 6;
    const int l0 = l & 1, l1 = (l >> 1) & 1, l2 = (l >> 2) & 1;
    const int l3 = (l >> 3) & 1, l4 = (l >> 4) & 1, l5 = (l >> 5) & 1;
    const int w0 = w & 1, w1 = (w >> 1) & 1, w2 = (w >> 2) & 1;
    const bool odd0 = l0;

    // Exchange/diag/store base addresses (idx-space), per the custody tables.
    const int b_w1 = l0*4 + l4*8 + l5*16 + l1*64 + l2*128 + l3*256
                   + w0*2048 + w1*4096 + w2*8192;                     // p2 layout
    const int b_r1 = w0*4 + w1*8 + w2*16 + l1*32 + l0*64 + l4*128
                   + l5*256 + l2*512 + l3*1024;                       // p3/p6 layout
    const int b_r2 = l0*32 + w0*64 + w1*128 + w2*256 + l4*512
                   + l5*1024 + l1*2048 + l2*4096 + l3*8192;           // p7/p10 layout
    const int b_r3 = l1*4 + l2*8 + l3*16 + w0*32 + w1*512 + w2*1024
                   + l0*2048 + l4*4096 + l5*8192;                     // p11 layout
    const int b_d1 = w0*4 + w1*8 + w2*16 + l1*32 + l2*512 + l3*1024
                   + l0*2048 + l4*4096 + l5*8192;                     // p4/p5 layout
    const int b_d2 = l0*4 + l4*8 + l5*16 + w0*64 + w1*128 + w2*256
                   + l1*2048 + l2*4096 + l3*8192;                     // p8/p9 layout
    const int b_st = l1*4 + l2*8 + l3*16 + w0*32 + l0*64 + l4*128
                   + l5*256 + w1*512 + w2*1024;                       // p12 layout

    const v2f negone = (v2f){-1.0f, -1.0f};
    v2f X[16];

    // ---------- prologue (T1: idx = t*32 + 4g + v) ----------
    if (t < 256) {                       // idx13 = w2 = 0 -> state half
        const float* srow = state + (size_t)r * NRES + t * 32;
        const float* d0   = diag + t * 32;
#pragma unroll
        for (int g = 0; g < 8; ++g) {
            float4 v = *(const float4*)(srow + 4 * g);
            float4 d = *(const float4*)(d0 + 4 * g);
            X[2*g]   = (v2f){0.9f * v.x * d.x, 0.9f * v.y * d.y};
            X[2*g+1] = (v2f){0.9f * v.z * d.z, 0.9f * v.w * d.w};
        }
    } else if (t < 258) {                // idx 8192..8255 -> inputs
        const float* irow = inputs + r * NINP + (t - 256) * 32;
        const float* d0   = diag + t * 32;
#pragma unroll
        for (int g = 0; g < 8; ++g) {
            float4 v = *(const float4*)(irow + 4 * g);
            float4 d = *(const float4*)(d0 + 4 * g);
            X[2*g]   = (v2f){0.4f * v.x * d.x, 0.4f * v.y * d.y};
            X[2*g+1] = (v2f){0.4f * v.z * d.z, 0.4f * v.w * d.w};
        }
    } else {
#pragma unroll
        for (int p = 0; p < 16; ++p) X[p] = (v2f){0.f, 0.f};
    }

    // ---------- layer 0 ----------
    vstage0(X); pstage<1>(X, negone);                 // idx 0,1
    jpass(X, negone);                                  // p1: idx 2,3,4
    shuffle_exchange(X, odd0);                         // S1
    jpass(X, negone);                                  // p2: idx 5,9,10

    { const int Q = physf(b_w1); WRX(Q, 32, 512, 1024); }   // L1 write
    BAR();
    { const int Q = physf(b_r1); RDX(Q, 2048, 4096, 8192); } // L1 read
    jpass(X, negone);                                  // p3: idx 11,12,13
    shuffle_exchange(X, odd0);                         // S2
    jpass(X, negone);                                  // p4: idx 6,7,8

    // ---------- layer 1 ----------
    DIAG_MUL(diag + NH + b_d1, 64, 128, 256);          // diag1
    vstage0(X); pstage<1>(X, negone);                  // idx 0,1
    jpass(X, negone);                                  // p5: idx 6,7,8
    shuffle_exchange(X, odd0);                         // S3
    jpass(X, negone);                                  // p6: idx 11,12,13

    BAR();                                             // protect L1 reads
    { const int Q = physf(b_r1); WRX(Q, 2048, 4096, 8192); } // L2 write
    BAR();
    { const int Q = physf(b_r2); RDX(Q, 4, 8, 16); }         // L2 read
    jpass(X, negone);                                  // p7: idx 2,3,4
    shuffle_exchange(X, odd0);                         // S4
    jpass(X, negone);                                  // p8: idx 5,9,10

    // ---------- layer 2 ----------
    DIAG_MUL(diag + 2 * NH + b_d2, 32, 512, 1024);     // diag2
    vstage0(X); pstage<1>(X, negone);                  // idx 0,1
    jpass(X, negone);                                  // p9: idx 5,9,10
    shuffle_exchange(X, odd0);                         // S5
    jpass(X, negone);                                  // p10: idx 2,3,4

    BAR();                                             // protect L2 reads
    { const int Q = physf(b_r2); WRX(Q, 4, 8, 16); }         // L3 write
    BAR();
    { const int Q = physf(b_r3); RDX(Q, 64, 128, 256); }     // L3 read
    jpass(X, negone);                                  // p11: idx 6,7,8
    shuffle_exchange(X, odd0);                         // S6
    jpass(X, negone);                                  // p12: idx 11,12,13

    // ---------- epilogue: idx13 = j2 = 0 -> g < 4; 16 floats/thread ----------
    {
        float* orow = out + (size_t)r * NRES;
        const float inv = 1.0f / (float)NH;
#pragma unroll
        for (int g = 0; g < 4; ++g) {
            const int a = b_st + (g & 1) * 2048 + (g >> 1) * 4096;
            float4 b = *(const float4*)(bias + a);
            float4 o;
            o.x = erf_fast(fmaf(X[2*g].x,   inv, b.x));
            o.y = erf_fast(fmaf(X[2*g].y,   inv, b.y));
            o.z = erf_fast(fmaf(X[2*g+1].x, inv, b.z));
            o.w = erf_fast(fmaf(X[2*g+1].y, inv, b.w));
            *(float4*)(orow + a) = o;
        }
    }
}

extern "C" void kernel_launch(void* const* d_in, const int* in_sizes, int n_in,
                              void* d_out, int out_size, void* d_ws, size_t ws_size,
                              hipStream_t stream) {
    (void)in_sizes; (void)n_in; (void)out_size; (void)d_ws; (void)ws_size;
    const float* state  = (const float*)d_in[0];
    const float* inputs = (const float*)d_in[1];
    const float* bias   = (const float*)d_in[2];
    const float* diag   = (const float*)d_in[3];
    float* out = (float*)d_out;

    hipLaunchKernelGGL(st_kernel, dim3(BATCH), dim3(512), 0, stream,
                       state, inputs, bias, diag, out);
}